// Round 7
// baseline (1216.707 us; speedup 1.0000x reference)
//
#include <hip/hip_runtime.h>
#include <hip/hip_fp16.h>

// N=512, C=3, T=300, V=25, M=2, F=150, H=100, gates=4H=400
// x element (n,c,t,v,m) at n*45000 + c*15000 + t*50 + (v*2+m)
// Weight-table column map: col = 4*j + k  <->  gate-row k*100+j (k: 0=i,1=f,2=g,3=o)
// Fused-K recurrence: gates = [Whh | Wih] @ [h ; x_t] + b, K = 256 (h:0..99, x:100..249, pad)

// ws layout (BYTE offsets):
#define B_W2P   0u          // uint[50][512]  dec folded Whh+Wih@fcW, f16-pair packed
#define B_WDP   102400u     // uint[50][512]  dec Whh (step-1)
#define B_WEP   204800u     // uint[50][512]  enc Whh
#define B_PIH   307200u     // uint[75][512]  enc Wih f16 pairs (K-pairs 50..124 of fused K)
#define B_BENC  460800u     // float[512]
#define B_B1    462848u     // float[512]
#define B_BEFF  464896u     // float[512]
#define B_HIST  466944u     // ushort hist[512][29952]
#define HIST_STRIDE 29952

typedef _Float16 h2_t __attribute__((ext_vector_type(2)));
typedef _Float16 f16x8 __attribute__((ext_vector_type(8)));
typedef float f32x4v __attribute__((ext_vector_type(4)));

#if defined(__has_builtin)
#if __has_builtin(__builtin_amdgcn_fdot2)
#define HAS_FDOT2 1
#endif
#endif

__device__ __forceinline__ float fdot2u(unsigned a, unsigned b, float c) {
#ifdef HAS_FDOT2
  return __builtin_amdgcn_fdot2(__builtin_bit_cast(h2_t, a), __builtin_bit_cast(h2_t, b), c, false);
#else
  float al = __half2float(__ushort_as_half((unsigned short)(a & 0xffffu)));
  float ah = __half2float(__ushort_as_half((unsigned short)(a >> 16)));
  float bl = __half2float(__ushort_as_half((unsigned short)(b & 0xffffu)));
  float bh = __half2float(__ushort_as_half((unsigned short)(b >> 16)));
  return fmaf(ah, bh, fmaf(al, bl, c));
#endif
}

__device__ __forceinline__ unsigned pack2f(float a, float b) {
  return (unsigned)__half_as_ushort(__float2half(a)) |
         ((unsigned)__half_as_ushort(__float2half(b)) << 16);
}

__device__ __forceinline__ float fast_sig(float x) {
  float e = __builtin_amdgcn_exp2f(x * -1.442695040888963f);
  return __builtin_amdgcn_rcpf(1.f + e);
}
__device__ __forceinline__ float fast_tanh(float x) {
  float e = __builtin_amdgcn_exp2f(x * -2.885390081777926f);
  return fmaf(2.f, __builtin_amdgcn_rcpf(1.f + e), -1.f);
}

__device__ __forceinline__ f32x4v mfma16(uint4 a, uint4 b, f32x4v c) {
  return __builtin_amdgcn_mfma_f32_16x16x32_f16(
      __builtin_bit_cast(f16x8, a), __builtin_bit_cast(f16x8, b), c, 0, 0, 0);
}

// ---------------- prep ----------------
__global__ void prep(const float* __restrict__ dWih, const float* __restrict__ dWhh,
                     const float* __restrict__ dbih, const float* __restrict__ dbhh,
                     const float* __restrict__ eWih, const float* __restrict__ eWhh,
                     const float* __restrict__ ebih, const float* __restrict__ ebhh,
                     const float* __restrict__ fcW,  const float* __restrict__ fcb,
                     char* __restrict__ wsb)
{
  int idx = blockIdx.x * 256 + threadIdx.x;
  if (idx < 25600) {                       // packed weight rows (pairs)
    int q = idx >> 9, t = idx & 511;
    unsigned w2p = 0, wdp = 0, wep = 0;
    if (t < 400) {
      int r = (t & 3) * 100 + (t >> 2);
      int j0 = 2 * q, j1 = 2 * q + 1;
      float wd0 = dWhh[r * 100 + j0], wd1 = dWhh[r * 100 + j1];
      float we0 = eWhh[r * 100 + j0], we1 = eWhh[r * 100 + j1];
      float s0 = 0.f, s1 = 0.f;
      for (int f = 0; f < 150; ++f) {
        float a = dWih[r * 150 + f];
        s0 = fmaf(a, fcW[f * 100 + j0], s0);
        s1 = fmaf(a, fcW[f * 100 + j1], s1);
      }
      w2p = pack2f(wd0 + s0, wd1 + s1);
      wdp = pack2f(wd0, wd1);
      wep = pack2f(we0, we1);
    }
    ((unsigned*)(wsb + B_W2P))[idx] = w2p;
    ((unsigned*)(wsb + B_WDP))[idx] = wdp;
    ((unsigned*)(wsb + B_WEP))[idx] = wep;
  } else if (idx < 25600 + 38400) {        // packed f16 enc_Wih
    int k = idx - 25600; int d = k >> 9, t = k & 511;
    unsigned pk = 0;
    if (t < 400) {
      int r = (t & 3) * 100 + (t >> 2);
      pk = pack2f(eWih[r * 150 + 2 * d], eWih[r * 150 + 2 * d + 1]);
    }
    ((unsigned*)(wsb + B_PIH))[k] = pk;
  } else if (idx < 25600 + 38400 + 512) {  // biases
    int t = idx - (25600 + 38400);
    float be = 0.f, b1 = 0.f, bf = 0.f;
    if (t < 400) {
      int r = (t & 3) * 100 + (t >> 2);
      be = ebih[r] + ebhh[r];
      b1 = dbih[r] + dbhh[r];
      float acc = 0.f;
      for (int f = 0; f < 150; ++f) acc = fmaf(dWih[r * 150 + f], fcb[f], acc);
      bf = b1 + acc;
    }
    ((float*)(wsb + B_BENC))[t] = be;
    ((float*)(wsb + B_B1))[t]   = b1;
    ((float*)(wsb + B_BEFF))[t] = bf;
  }
}

// ---------------- recurrent: fused-K MFMA, one dispatch, 599 steps ----------------
// 32 blocks x 16 samples, 8 waves (balanced 2/SIMD). Wave w owns tiles {w+8i}.
// lane(sp=lane&15,q=lane>>4). Encoder: K=256 fused [h|x_t|pad], 8 K-steps.
// x pipeline is 2 steps deep: x(t+1) (in regs) is written to hx[wr] FIRST thing in
// step t (that buffer's readers finished before the barrier we just crossed), then
// loads for x(t+2) issue -> a full step (~1us) covers HBM latency.
// Decoder: K=128 (h|pad), 4 K-steps, zero-padded A beyond pair 50.
// D-frag lane-local: acc = (i,f,g,o) of cell 4*tile+q, sample sp -> no shuffles.
__global__ __launch_bounds__(512)
void recurrent(const float* __restrict__ x, char* __restrict__ wsb)
{
  const int tid  = threadIdx.x;
  const int w    = tid >> 6;
  const int lane = tid & 63;
  const int sp   = lane & 15;
  const int q    = lane >> 4;
  const int nb   = blockIdx.x * 16;

  __shared__ unsigned short hx[2][16][264];  // [buf][sample][K(256)+pad], f16
  for (int k = tid; k < 2 * 16 * 264; k += 512) ((unsigned short*)hx)[k] = 0;

  const unsigned* WEP = (const unsigned*)(wsb + B_WEP);
  const unsigned* WDP = (const unsigned*)(wsb + B_WDP);
  const unsigned* W2P = (const unsigned*)(wsb + B_W2P);
  const unsigned* PIH = (const unsigned*)(wsb + B_PIH);

  const int nt = (w == 0) ? 4 : 3;          // tiles this wave owns (4+7*3=25)
  int cells[4];
  float4 bs[4];
  uint4 af[4][8];
#pragma unroll
  for (int i = 0; i < 4; ++i) {
    const int tile = (i < nt) ? (w + 8 * i) : 0;
    const int col = tile * 16 + sp;
    cells[i] = 4 * tile + q;
#pragma unroll
    for (int kk = 0; kk < 8; ++kk) {
      unsigned e[4];
#pragma unroll
      for (int l = 0; l < 4; ++l) {
        const int p = kk * 16 + q * 4 + l;   // fused K-pair index
        unsigned v = 0u;
        if (p < 50) v = WEP[p * 512 + col];
        else if (p < 125) v = PIH[(p - 50) * 512 + col];
        e[l] = v;
      }
      af[i][kk] = make_uint4(e[0], e[1], e[2], e[3]);
    }
    bs[i] = ((const float4*)(wsb + B_BENC))[cells[i]];
  }

  // x staging map: threads 0..399 -> (sample ssp, 6 features starting at 6*sr)
  const bool stg = tid < 400;
  const int ssp = tid / 25;
  const int sr  = tid - ssp * 25;
  const float* xb = x + (size_t)(nb + (stg ? ssp : 0)) * 45000;
  int soff[6];
#pragma unroll
  for (int l = 0; l < 6; ++l) {
    const int f = sr * 6 + l;
    const int cd = f / 50;
    soff[l] = cd * 15000 + (f - cd * 50);
  }
  const int sdst = (stg ? ssp : 0) * 264 + 100 + sr * 6;  // ushort idx in buffer

  unsigned short* histn = (unsigned short*)(wsb + B_HIST) + (size_t)(nb + sp) * HIST_STRIDE;

  // prologue: zeros visible, stage x(0) into buf0, preload x(1) into regs
  __syncthreads();
  float xW[6];
  if (stg) {
    float x0[6];
#pragma unroll
    for (int l = 0; l < 6; ++l) x0[l] = xb[soff[l]];
    unsigned short* d = &hx[0][0][0] + sdst;
    *(unsigned*)(d + 0) = pack2f(x0[0], x0[1]);
    *(unsigned*)(d + 2) = pack2f(x0[2], x0[3]);
    *(unsigned*)(d + 4) = pack2f(x0[4], x0[5]);
#pragma unroll
    for (int l = 0; l < 6; ++l) xW[l] = xb[soff[l] + 50];   // x(1)
  }
  __syncthreads();

  float cst[4] = {0.f, 0.f, 0.f, 0.f};

  // ---- encoder: 300 steps, K=256 ----
  for (int t = 0; t < 300; ++t) {
    const int rd = t & 1, wr = rd ^ 1;
    // (1) write x(t+1) from regs into next buffer — first action of the step
    if (stg && t < 299) {
      unsigned short* d = &hx[wr][0][0] + sdst;
      *(unsigned*)(d + 0) = pack2f(xW[0], xW[1]);
      *(unsigned*)(d + 2) = pack2f(xW[2], xW[3]);
      *(unsigned*)(d + 4) = pack2f(xW[4], xW[5]);
    }
    // (2) issue loads for x(t+2) — a full step to cover HBM latency
    float xL[6];
    if (stg && t < 298) {
      const int to = (t + 2) * 50;
#pragma unroll
      for (int l = 0; l < 6; ++l) xL[l] = xb[soff[l] + to];
    }
    // (3) MFMA over fused K
    f32x4v acc[4];
#pragma unroll
    for (int i = 0; i < 4; ++i) {
      acc[i][0] = bs[i].x; acc[i][1] = bs[i].y;
      acc[i][2] = bs[i].z; acc[i][3] = bs[i].w;
    }
#pragma unroll
    for (int kk = 0; kk < 8; ++kk) {
      uint4 b = *(const uint4*)(&hx[rd][sp][kk * 32 + q * 8]);
#pragma unroll
      for (int i = 0; i < 4; ++i)
        if (i < nt) acc[i] = mfma16(af[i][kk], b, acc[i]);
    }
    // (4) lane-local tails + h write
#pragma unroll
    for (int i = 0; i < 4; ++i) {
      if (i < nt) {
        float ii = fast_sig(acc[i][0]), ff = fast_sig(acc[i][1]);
        float gg = fast_tanh(acc[i][2]), oo = fast_sig(acc[i][3]);
        cst[i] = fmaf(ff, cst[i], ii * gg);
        float h = oo * fast_tanh(cst[i]);
        hx[wr][sp][cells[i]] = __half_as_ushort(__float2half(h));
      }
    }
    __syncthreads();
    if (stg) {
#pragma unroll
      for (int l = 0; l < 6; ++l) xW[l] = xL[l];
    }
  }

  // ---- decoder A-frag reload helper (K=128, zero beyond pair 50) ----
  auto loadA4 = [&](const unsigned* W, unsigned bofs) {
#pragma unroll
    for (int i = 0; i < 4; ++i) {
      const int tile = (i < nt) ? (w + 8 * i) : 0;
      const int col = tile * 16 + sp;
#pragma unroll
      for (int kk = 0; kk < 4; ++kk) {
        unsigned e[4];
#pragma unroll
        for (int l = 0; l < 4; ++l) {
          const int p = kk * 16 + q * 4 + l;
          e[l] = (p < 50) ? W[p * 512 + col] : 0u;
        }
        af[i][kk] = make_uint4(e[0], e[1], e[2], e[3]);
      }
      bs[i] = ((const float4*)(wsb + bofs))[cells[i]];
    }
  };

  // decoder step 1: plain Whh (input zeros); enc final h is in hx[0]
  loadA4(WDP, B_B1);
  {
    f32x4v acc[4];
#pragma unroll
    for (int i = 0; i < 4; ++i) {
      acc[i][0] = bs[i].x; acc[i][1] = bs[i].y;
      acc[i][2] = bs[i].z; acc[i][3] = bs[i].w;
    }
#pragma unroll
    for (int kk = 0; kk < 4; ++kk) {
      uint4 b = *(const uint4*)(&hx[0][sp][kk * 32 + q * 8]);
#pragma unroll
      for (int i = 0; i < 4; ++i)
        if (i < nt) acc[i] = mfma16(af[i][kk], b, acc[i]);
    }
#pragma unroll
    for (int i = 0; i < 4; ++i) {
      if (i < nt) {
        float ii = fast_sig(acc[i][0]), ff = fast_sig(acc[i][1]);
        float gg = fast_tanh(acc[i][2]), oo = fast_sig(acc[i][3]);
        cst[i] = fmaf(ff, cst[i], ii * gg);
        float h = oo * fast_tanh(cst[i]);
        hx[1][sp][cells[i]] = __half_as_ushort(__float2half(h));
        histn[cells[i]] = __half_as_ushort(__float2half(h));
      }
    }
    __syncthreads();
  }
  // decoder steps 2..299: folded W2
  loadA4(W2P, B_BEFF);
  for (int s = 2; s <= 299; ++s) {
    const int rd = (299 + s) & 1, wr = rd ^ 1;
    f32x4v acc[4];
#pragma unroll
    for (int i = 0; i < 4; ++i) {
      acc[i][0] = bs[i].x; acc[i][1] = bs[i].y;
      acc[i][2] = bs[i].z; acc[i][3] = bs[i].w;
    }
#pragma unroll
    for (int kk = 0; kk < 4; ++kk) {
      uint4 b = *(const uint4*)(&hx[rd][sp][kk * 32 + q * 8]);
#pragma unroll
      for (int i = 0; i < 4; ++i)
        if (i < nt) acc[i] = mfma16(af[i][kk], b, acc[i]);
    }
#pragma unroll
    for (int i = 0; i < 4; ++i) {
      if (i < nt) {
        float ii = fast_sig(acc[i][0]), ff = fast_sig(acc[i][1]);
        float gg = fast_tanh(acc[i][2]), oo = fast_sig(acc[i][3]);
        cst[i] = fmaf(ff, cst[i], ii * gg);
        float h = oo * fast_tanh(cst[i]);
        hx[wr][sp][cells[i]] = __half_as_ushort(__float2half(h));
        histn[(s - 1) * 100 + cells[i]] = __half_as_ushort(__float2half(h));
      }
    }
    __syncthreads();
  }
}

// ---------------- emit: out[n][t] = fcW @ h_{t-1} + fcb ----------------
__global__ __launch_bounds__(192, 4)
void emit(const char* __restrict__ wsb, const float* __restrict__ fcW,
          const float* __restrict__ fcb, float* __restrict__ out)
{
  const int f = threadIdx.x;
  const int n = blockIdx.x;
  const int z = blockIdx.y;
  __shared__ unsigned short hl[15008];

  const uint4* src = (const uint4*)((const unsigned short*)(wsb + B_HIST) +
                                    (size_t)n * HIST_STRIDE + z * 15000);
  for (int k = f; k < 1875; k += 192) ((uint4*)hl)[k] = src[k];

  const bool on = f < 150;
  unsigned fw[50];
  float bias = 0.f;
  if (on) {
    const float* fp = fcW + f * 100;
#pragma unroll
    for (int q = 0; q < 50; ++q) fw[q] = pack2f(fp[2 * q], fp[2 * q + 1]);
    bias = fcb[f];
  }
  __syncthreads();

  if (!on) return;
  const int cc = f / 50, r = f - cc * 50;
  float* ob = out + (size_t)n * 45000 + cc * 15000 + r;
  if (z == 0) ob[0] = 0.f;
  const int rows = z ? 149 : 150;
  for (int tl = 0; tl < rows; ++tl) {
    const uint4* row = (const uint4*)(hl + tl * 100);
    float a0 = bias, a1 = 0.f, a2 = 0.f, a3 = 0.f;
#pragma unroll
    for (int ch = 0; ch < 12; ++ch) {
      uint4 v = row[ch];
      a0 = fdot2u(fw[4 * ch + 0], v.x, a0);
      a1 = fdot2u(fw[4 * ch + 1], v.y, a1);
      a2 = fdot2u(fw[4 * ch + 2], v.z, a2);
      a3 = fdot2u(fw[4 * ch + 3], v.w, a3);
    }
    uint2 v2 = *(const uint2*)(hl + tl * 100 + 96);
    a0 = fdot2u(fw[48], v2.x, a0);
    a1 = fdot2u(fw[49], v2.y, a1);
    const int tt = z * 150 + tl + 1;
    ob[tt * 50] = (a0 + a1) + (a2 + a3);
  }
}

extern "C" void kernel_launch(void* const* d_in, const int* in_sizes, int n_in,
                              void* d_out, int out_size, void* d_ws, size_t ws_size,
                              hipStream_t stream) {
  const float* x    = (const float*)d_in[0];
  const float* eWih = (const float*)d_in[1];
  const float* eWhh = (const float*)d_in[2];
  const float* ebih = (const float*)d_in[3];
  const float* ebhh = (const float*)d_in[4];
  const float* dWih = (const float*)d_in[5];
  const float* dWhh = (const float*)d_in[6];
  const float* dbih = (const float*)d_in[7];
  const float* dbhh = (const float*)d_in[8];
  const float* fcW  = (const float*)d_in[9];
  const float* fcb  = (const float*)d_in[10];
  float* out = (float*)d_out;
  char* wsb  = (char*)d_ws;

  prep<<<252, 256, 0, stream>>>(dWih, dWhh, dbih, dbhh, eWih, eWhh, ebih, ebhh, fcW, fcb, wsb);
  // fused-K recurrence: no pre, no xg, no phase split — one 599-step dispatch
  recurrent<<<32, 512, 0, stream>>>(x, wsb);
  emit<<<dim3(512, 2), 192, 0, stream>>>(wsb, fcW, fcb, out);
}